// Round 1
// baseline (219.385 us; speedup 1.0000x reference)
//
#include <hip/hip_runtime.h>

#define MM 4096
#define NN 4096
#define KK 4096

typedef short          s16x8 __attribute__((ext_vector_type(8)));
typedef float          f32x4 __attribute__((ext_vector_type(4)));
typedef unsigned short us4   __attribute__((ext_vector_type(4)));
typedef unsigned short us8   __attribute__((ext_vector_type(8)));

// ---------- helpers ----------

__device__ __forceinline__ unsigned short f2bf(float f) {
  // round-to-nearest-even f32 -> bf16 (no NaN handling needed: inputs are finite normals)
  unsigned int u = __float_as_uint(f);
  u += 0x7fffu + ((u >> 16) & 1u);
  return (unsigned short)(u >> 16);
}

__device__ __forceinline__ void gload16(const void* g, void* l) {
  // async global->LDS, 16B per lane; LDS dest is wave-uniform base + lane*16
  __builtin_amdgcn_global_load_lds(
      (const __attribute__((address_space(1))) void*)g,
      (__attribute__((address_space(3))) void*)l, 16, 0, 0);
}

// ---------- kernel 1: 2:4 mask + binarize + cvt -> bf16 W_h (M x K) ----------

__global__ __launch_bounds__(256) void kquant(const float* __restrict__ w,
                                              unsigned short* __restrict__ wh) {
  int idx = blockIdx.x * 256 + threadIdx.x;      // one thread per 8 elements (2 groups of 4)
  const float4* p = (const float4*)w;
  float4 g0 = p[(size_t)idx * 2];
  float4 g1 = p[(size_t)idx * 2 + 1];
  float v[8] = {g0.x, g0.y, g0.z, g0.w, g1.x, g1.y, g1.z, g1.w};
  us8 o;
#pragma unroll
  for (int g = 0; g < 2; g++) {
    float av[4];
#pragma unroll
    for (int j = 0; j < 4; j++) av[j] = fabsf(v[g * 4 + j]);
#pragma unroll
    for (int j = 0; j < 4; j++) {
      int rank = 0;
#pragma unroll
      for (int k = 0; k < 4; k++) {
        if (k == j) continue;
        // matches jax.lax.top_k tie-break: lower index wins
        rank += (av[k] > av[j] || (av[k] == av[j] && k < j)) ? 1 : 0;
      }
      o[g * 4 + j] = (rank < 2 && v[g * 4 + j] > 0.0f) ? (unsigned short)0x3F80
                                                       : (unsigned short)0;
    }
  }
  *(us8*)(wh + (size_t)idx * 8) = o;
}

// ---------- kernel 2: x (K x N f32) -> xT (N x K bf16) ----------

__global__ __launch_bounds__(256) void ktranspose(const float* __restrict__ x,
                                                  unsigned short* __restrict__ xt) {
  __shared__ float tile[64][65];
  int bn = blockIdx.x;            // n tile
  int bk = blockIdx.y;            // k tile
  int t = threadIdx.x;
  int tc = (t & 15) << 2;         // 0..60 step 4
  int tr = t >> 4;                // 0..15
  const float* src = x + (size_t)(bk * 64 + tr) * NN + bn * 64 + tc;
#pragma unroll
  for (int i = 0; i < 4; i++) {
    float4 v = *(const float4*)(src + (size_t)i * 16 * NN);
    int r = tr + i * 16;
    tile[r][tc + 0] = v.x; tile[r][tc + 1] = v.y;
    tile[r][tc + 2] = v.z; tile[r][tc + 3] = v.w;
  }
  __syncthreads();
  unsigned short* dst = xt + (size_t)(bn * 64 + tr) * KK + bk * 64 + tc;
#pragma unroll
  for (int i = 0; i < 4; i++) {
    int n = tr + i * 16;
    us4 o;
    o.x = f2bf(tile[tc + 0][n]);
    o.y = f2bf(tile[tc + 1][n]);
    o.z = f2bf(tile[tc + 2][n]);
    o.w = f2bf(tile[tc + 3][n]);
    *(us4*)(dst + (size_t)i * 16 * KK) = o;
  }
}

// ---------- kernel 3: C (M x N f32) = W_h (M x K) @ xT (N x K)^T ----------
// m97 structure: 128x128 tile, BK=32, 4 waves (2x2), 16x16x32 bf16 MFMA,
// global_load_lds width-16 staging, ds_read_b128 fragments.

__global__ __launch_bounds__(256) void kgemm(const unsigned short* __restrict__ A,
                                             const unsigned short* __restrict__ B,
                                             float* __restrict__ C) {
  __shared__ __align__(16) unsigned short sA[128 * 32];
  __shared__ __align__(16) unsigned short sB[128 * 32];

  const int tid  = threadIdx.x;
  const int bm   = blockIdx.y;
  const int bn   = blockIdx.x;
  const int lane = tid & 63;
  const int wave = tid >> 6;
  const int wr   = wave >> 1;    // wave row (0..1)
  const int wc   = wave & 1;     // wave col (0..1)
  const int llo  = lane & 15;
  const int lhi  = lane >> 4;

  // staging: 256 threads x 16B x 2 iters per tile (8KB)
  const int r0 = tid >> 2;               // row 0..63
  const int c8 = (tid & 3) << 3;         // k elem offset 0/8/16/24
  const unsigned short* a0 = A + (size_t)(bm * 128 + r0) * KK + c8;
  const unsigned short* a1 = a0 + (size_t)64 * KK;
  const unsigned short* b0 = B + (size_t)(bn * 128 + r0) * KK + c8;
  const unsigned short* b1 = b0 + (size_t)64 * KK;
  unsigned short* da0 = &sA[tid * 8];
  unsigned short* da1 = &sA[tid * 8 + 2048];
  unsigned short* db0 = &sB[tid * 8];
  unsigned short* db1 = &sB[tid * 8 + 2048];

  f32x4 acc[4][4] = {};

  const unsigned short* pa = &sA[(wr * 64 + llo) * 32 + lhi * 8];
  const unsigned short* pb = &sB[(wc * 64 + llo) * 32 + lhi * 8];

  for (int k0 = 0; k0 < KK; k0 += 32) {
    __syncthreads();                       // previous compute done before overwrite
    gload16(a0 + k0, da0);
    gload16(a1 + k0, da1);
    gload16(b0 + k0, db0);
    gload16(b1 + k0, db1);
    __syncthreads();                       // staging complete (compiler drains vmcnt)

    s16x8 af[4], bf[4];
#pragma unroll
    for (int m = 0; m < 4; m++) af[m] = *(const s16x8*)(pa + m * 16 * 32);
#pragma unroll
    for (int n = 0; n < 4; n++) bf[n] = *(const s16x8*)(pb + n * 16 * 32);
#pragma unroll
    for (int m = 0; m < 4; m++)
#pragma unroll
      for (int n = 0; n < 4; n++)
        acc[m][n] = __builtin_amdgcn_mfma_f32_16x16x32_bf16(af[m], bf[n], acc[m][n], 0, 0, 0);
  }

  // epilogue: D layout col = lane&15, row = (lane>>4)*4 + reg (m89-verified)
#pragma unroll
  for (int m = 0; m < 4; m++) {
    int r = bm * 128 + wr * 64 + m * 16 + lhi * 4;
#pragma unroll
    for (int n = 0; n < 4; n++) {
      int cidx = bn * 128 + wc * 64 + n * 16 + llo;
      float* cp = C + (size_t)r * NN + cidx;
#pragma unroll
      for (int v = 0; v < 4; v++) cp[(size_t)v * NN] = acc[m][n][v];
    }
  }
}

// ---------- fallback (only if workspace too small): fused fp32 tiled GEMM ----------

__device__ __forceinline__ float binq_elem(const float g[4], int j) {
  float aj = fabsf(g[j]);
  int rank = 0;
#pragma unroll
  for (int k = 0; k < 4; k++) {
    if (k == j) continue;
    float ak = fabsf(g[k]);
    rank += (ak > aj || (ak == aj && k < j)) ? 1 : 0;
  }
  return (rank < 2 && g[j] > 0.0f) ? 1.0f : 0.0f;
}

__global__ __launch_bounds__(256) void kfallback(const float* __restrict__ x,
                                                 const float* __restrict__ w,
                                                 float* __restrict__ c) {
  __shared__ float sA[16][17];
  __shared__ float sB[16][17];
  int tx = threadIdx.x, ty = threadIdx.y;
  int row = blockIdx.y * 16 + ty;   // o
  int col = blockIdx.x * 16 + tx;   // n
  float acc = 0.0f;
  for (int k0 = 0; k0 < KK; k0 += 16) {
    int k = k0 + tx;
    const float* g = &w[(size_t)row * KK + (k & ~3)];
    float gv[4] = {g[0], g[1], g[2], g[3]};
    sA[ty][tx] = binq_elem(gv, k & 3);
    sB[ty][tx] = x[(size_t)(k0 + ty) * NN + col];
    __syncthreads();
#pragma unroll
    for (int kk = 0; kk < 16; kk++) acc += sA[ty][kk] * sB[kk][tx];
    __syncthreads();
  }
  c[(size_t)row * NN + col] = acc;
}

// ---------- launcher ----------

extern "C" void kernel_launch(void* const* d_in, const int* in_sizes, int n_in,
                              void* d_out, int out_size, void* d_ws, size_t ws_size,
                              hipStream_t stream) {
  const float* x = (const float*)d_in[0];       // (K=4096, N=4096) f32
  const float* w = (const float*)d_in[1];       // (M=4096, K=4096) f32
  float* out = (float*)d_out;                   // (M, N) f32

  const size_t need = (size_t)MM * KK * 2 + (size_t)NN * KK * 2;  // 64 MB
  if (ws_size < need) {
    dim3 blk(16, 16);
    dim3 grd(NN / 16, MM / 16);
    kfallback<<<grd, blk, 0, stream>>>(x, w, out);
    return;
  }

  unsigned short* wh = (unsigned short*)d_ws;              // M x K bf16
  unsigned short* xt = wh + (size_t)MM * KK;               // N x K bf16

  kquant<<<(MM * (size_t)KK / 8) / 256, 256, 0, stream>>>(w, wh);
  ktranspose<<<dim3(NN / 64, KK / 64), 256, 0, stream>>>(x, xt);
  kgemm<<<dim3(NN / 128, MM / 128), 256, 0, stream>>>(wh, xt, out);
}

// Round 2
// 156.206 us; speedup vs baseline: 1.4045x; 1.4045x over previous
//
#include <hip/hip_runtime.h>

#define MM 4096
#define NN 4096
#define KK 4096
#define BM 256
#define BN 256
#define BK 64
#define NT (KK / BK)

typedef short          s16x8 __attribute__((ext_vector_type(8)));
typedef float          f32x4 __attribute__((ext_vector_type(4)));
typedef unsigned short us4   __attribute__((ext_vector_type(4)));
typedef unsigned short us8   __attribute__((ext_vector_type(8)));

#define MFMA16(a, b, c) __builtin_amdgcn_mfma_f32_16x16x32_bf16((a), (b), (c), 0, 0, 0)

// ---------- helpers ----------

__device__ __forceinline__ unsigned short f2bf(float f) {
  unsigned int u = __float_as_uint(f);
  u += 0x7fffu + ((u >> 16) & 1u);
  return (unsigned short)(u >> 16);
}

__device__ __forceinline__ void gload16(const void* g, void* l) {
  __builtin_amdgcn_global_load_lds(
      (const __attribute__((address_space(1))) void*)g,
      (__attribute__((address_space(3))) void*)l, 16, 0, 0);
}

// ---------- kernel 1: 2:4 mask + binarize + cvt -> bf16 W_h (M x K) ----------

__global__ __launch_bounds__(256) void kquant(const float* __restrict__ w,
                                              unsigned short* __restrict__ wh) {
  int idx = blockIdx.x * 256 + threadIdx.x;
  const float4* p = (const float4*)w;
  float4 g0 = p[(size_t)idx * 2];
  float4 g1 = p[(size_t)idx * 2 + 1];
  float v[8] = {g0.x, g0.y, g0.z, g0.w, g1.x, g1.y, g1.z, g1.w};
  us8 o;
#pragma unroll
  for (int g = 0; g < 2; g++) {
    float av[4];
#pragma unroll
    for (int j = 0; j < 4; j++) av[j] = fabsf(v[g * 4 + j]);
#pragma unroll
    for (int j = 0; j < 4; j++) {
      int rank = 0;
#pragma unroll
      for (int k = 0; k < 4; k++) {
        if (k == j) continue;
        rank += (av[k] > av[j] || (av[k] == av[j] && k < j)) ? 1 : 0;
      }
      o[g * 4 + j] = (rank < 2 && v[g * 4 + j] > 0.0f) ? (unsigned short)0x3F80
                                                       : (unsigned short)0;
    }
  }
  *(us8*)(wh + (size_t)idx * 8) = o;
}

// ---------- kernel 2: x (K x N f32) -> xT (N x K bf16) ----------

__global__ __launch_bounds__(256) void ktranspose(const float* __restrict__ x,
                                                  unsigned short* __restrict__ xt) {
  __shared__ float tile[64][65];
  int bn = blockIdx.x;
  int bk = blockIdx.y;
  int t = threadIdx.x;
  int tc = (t & 15) << 2;
  int tr = t >> 4;
  const float* src = x + (size_t)(bk * 64 + tr) * NN + bn * 64 + tc;
#pragma unroll
  for (int i = 0; i < 4; i++) {
    float4 v = *(const float4*)(src + (size_t)i * 16 * NN);
    int r = tr + i * 16;
    tile[r][tc + 0] = v.x; tile[r][tc + 1] = v.y;
    tile[r][tc + 2] = v.z; tile[r][tc + 3] = v.w;
  }
  __syncthreads();
  unsigned short* dst = xt + (size_t)(bn * 64 + tr) * KK + bk * 64 + tc;
#pragma unroll
  for (int i = 0; i < 4; i++) {
    int n = tr + i * 16;
    us4 o;
    o.x = f2bf(tile[tc + 0][n]);
    o.y = f2bf(tile[tc + 1][n]);
    o.z = f2bf(tile[tc + 2][n]);
    o.w = f2bf(tile[tc + 3][n]);
    *(us4*)(dst + (size_t)i * 16 * KK) = o;
  }
}

// ---------- kernel 3: 256x256 8-phase GEMM, C = W_h @ xT^T ----------
// 8 waves (2M x 4N), BK=64, double-buffered LDS (128 KiB), counted vmcnt,
// T2 XOR-swizzle (linear gload_lds dest + pre-swizzled global src + swizzled
// ds_read), T5 setprio around each 16-MFMA phase cluster.

__global__ __launch_bounds__(512, 2) void kgemm(const unsigned short* __restrict__ A,
                                                const unsigned short* __restrict__ B,
                                                float* __restrict__ C) {
  __shared__ __align__(16) unsigned short lds[4 * BM * BK];  // A0,A1,B0,B1 = 128 KiB

  const int tid  = threadIdx.x;
  const int bmi  = blockIdx.y;
  const int bni  = blockIdx.x;
  const int lane = tid & 63;
  const int wave = tid >> 6;
  const int wm   = wave >> 2;      // 0..1
  const int wn   = wave & 3;       // 0..3
  const int llo  = lane & 15;
  const int lhi  = lane >> 4;

  // --- staging addresses (linear LDS dest; inverse-swizzled global source) ---
  const int srow  = tid >> 3;                     // 0..63 within each 64-row chunk
  const int scol  = (tid & 7) << 3;               // elem col 0..56
  const int scolz = scol ^ ((srow & 7) << 3);     // pre-swizzled source col
  const unsigned short* ga = A + (size_t)(bmi * BM + srow) * KK + scolz;
  const unsigned short* gb = B + (size_t)(bni * BN + srow) * KK + scolz;

  // --- fragment read offsets (swizzled) ---
  const int swz  = (llo & 7) << 3;
  const int ok0  = (lhi * 8) ^ swz;               // kk=0 column
  const int ok1  = (32 + lhi * 8) ^ swz;          // kk=1 column
  const int arow = (wm * 128 + llo) * BK;         // + mi*16*BK
  const int brow = (wn * 64 + llo) * BK;          // + ni*16*BK

  f32x4 acc[8][4] = {};

  auto stage = [&](int buf, int t) {
    const unsigned short* pa = ga + t * BK;
    const unsigned short* pb = gb + t * BK;
    unsigned short* la = &lds[buf * (BM * BK) + tid * 8];
    unsigned short* lb = &lds[2 * BM * BK + buf * (BN * BK) + tid * 8];
#pragma unroll
    for (int j = 0; j < 4; j++) {
      gload16(pa + (size_t)j * 64 * KK, la + j * 4096);
      gload16(pb + (size_t)j * 64 * KK, lb + j * 4096);
    }
  };

  stage(0, 0);  // prologue: tile 0 -> buf0 (8 loads in flight)

  for (int t = 0; t < NT; ++t) {
    const int cur = t & 1;
    const unsigned short* sa = &lds[cur * (BM * BK)];
    const unsigned short* sb = &lds[2 * BM * BK + cur * (BN * BK)];

    if (t + 1 < NT) {
      stage(cur ^ 1, t + 1);                          // 8 loads for tile t+1
      asm volatile("s_waitcnt vmcnt(8)" ::: "memory"); // tile t landed; t+1 in flight
    } else {
      asm volatile("s_waitcnt vmcnt(0)" ::: "memory");
    }
    __builtin_amdgcn_s_barrier();                      // collective: tile t ready

    s16x8 af[4][2], b0[2][2], b1[2][2];

    // ---- phase 1: read A(qm=0) [8] + B(qn=0) [4]; compute quadrant (0,0) ----
#pragma unroll
    for (int m = 0; m < 4; m++) {
      af[m][0] = *(const s16x8*)(sa + arow + m * 16 * BK + ok0);
      af[m][1] = *(const s16x8*)(sa + arow + m * 16 * BK + ok1);
    }
#pragma unroll
    for (int n = 0; n < 2; n++) {
      b0[n][0] = *(const s16x8*)(sb + brow + n * 16 * BK + ok0);
      b0[n][1] = *(const s16x8*)(sb + brow + n * 16 * BK + ok1);
    }
    __builtin_amdgcn_s_barrier();
    asm volatile("s_waitcnt lgkmcnt(0)" ::: "memory");
    __builtin_amdgcn_sched_barrier(0);
    __builtin_amdgcn_s_setprio(1);
#pragma unroll
    for (int m = 0; m < 4; m++)
#pragma unroll
      for (int n = 0; n < 2; n++) {
        acc[m][n] = MFMA16(af[m][0], b0[n][0], acc[m][n]);
        acc[m][n] = MFMA16(af[m][1], b0[n][1], acc[m][n]);
      }
    __builtin_amdgcn_s_setprio(0);
    __builtin_amdgcn_s_barrier();

    // ---- phase 2: read B(qn=1) [4]; compute quadrant (0,1) ----
#pragma unroll
    for (int n = 0; n < 2; n++) {
      b1[n][0] = *(const s16x8*)(sb + brow + (32 + n * 16) * BK + ok0);
      b1[n][1] = *(const s16x8*)(sb + brow + (32 + n * 16) * BK + ok1);
    }
    __builtin_amdgcn_s_barrier();
    asm volatile("s_waitcnt lgkmcnt(0)" ::: "memory");
    __builtin_amdgcn_sched_barrier(0);
    __builtin_amdgcn_s_setprio(1);
#pragma unroll
    for (int m = 0; m < 4; m++)
#pragma unroll
      for (int n = 0; n < 2; n++) {
        acc[m][2 + n] = MFMA16(af[m][0], b1[n][0], acc[m][2 + n]);
        acc[m][2 + n] = MFMA16(af[m][1], b1[n][1], acc[m][2 + n]);
      }
    __builtin_amdgcn_s_setprio(0);
    __builtin_amdgcn_s_barrier();

    // ---- phase 3: read A(qm=1) [8] (reuse af regs); compute quadrant (1,0) ----
#pragma unroll
    for (int m = 0; m < 4; m++) {
      af[m][0] = *(const s16x8*)(sa + arow + (64 + m * 16) * BK + ok0);
      af[m][1] = *(const s16x8*)(sa + arow + (64 + m * 16) * BK + ok1);
    }
    __builtin_amdgcn_s_barrier();
    asm volatile("s_waitcnt lgkmcnt(0)" ::: "memory");
    __builtin_amdgcn_sched_barrier(0);
    __builtin_amdgcn_s_setprio(1);
#pragma unroll
    for (int m = 0; m < 4; m++)
#pragma unroll
      for (int n = 0; n < 2; n++) {
        acc[4 + m][n] = MFMA16(af[m][0], b0[n][0], acc[4 + m][n]);
        acc[4 + m][n] = MFMA16(af[m][1], b0[n][1], acc[4 + m][n]);
      }
    __builtin_amdgcn_s_setprio(0);
    __builtin_amdgcn_s_barrier();

    // ---- phase 4: no reads; compute quadrant (1,1) ----
    __builtin_amdgcn_s_setprio(1);
#pragma unroll
    for (int m = 0; m < 4; m++)
#pragma unroll
      for (int n = 0; n < 2; n++) {
        acc[4 + m][2 + n] = MFMA16(af[m][0], b1[n][0], acc[4 + m][2 + n]);
        acc[4 + m][2 + n] = MFMA16(af[m][1], b1[n][1], acc[4 + m][2 + n]);
      }
    __builtin_amdgcn_s_setprio(0);
    __builtin_amdgcn_s_barrier();
  }

  // ---- epilogue: D layout col = lane&15, row = (lane>>4)*4 + reg ----
  const int crow0 = bmi * BM + wm * 128 + lhi * 4;
  const int ccol0 = bni * BN + wn * 64 + llo;
#pragma unroll
  for (int m = 0; m < 8; m++)
#pragma unroll
    for (int n = 0; n < 4; n++) {
      float* cp = C + (size_t)(crow0 + m * 16) * NN + ccol0 + n * 16;
#pragma unroll
      for (int v = 0; v < 4; v++) cp[(size_t)v * NN] = acc[m][n][v];
    }
}

// ---------- fallback: fused fp32 tiled GEMM (workspace too small) ----------

__device__ __forceinline__ float binq_elem(const float g[4], int j) {
  float aj = fabsf(g[j]);
  int rank = 0;
#pragma unroll
  for (int k = 0; k < 4; k++) {
    if (k == j) continue;
    float ak = fabsf(g[k]);
    rank += (ak > aj || (ak == aj && k < j)) ? 1 : 0;
  }
  return (rank < 2 && g[j] > 0.0f) ? 1.0f : 0.0f;
}

__global__ __launch_bounds__(256) void kfallback(const float* __restrict__ x,
                                                 const float* __restrict__ w,
                                                 float* __restrict__ c) {
  __shared__ float sA[16][17];
  __shared__ float sB[16][17];
  int tx = threadIdx.x, ty = threadIdx.y;
  int row = blockIdx.y * 16 + ty;
  int col = blockIdx.x * 16 + tx;
  float acc = 0.0f;
  for (int k0 = 0; k0 < KK; k0 += 16) {
    int k = k0 + tx;
    const float* g = &w[(size_t)row * KK + (k & ~3)];
    float gv[4] = {g[0], g[1], g[2], g[3]};
    sA[ty][tx] = binq_elem(gv, k & 3);
    sB[ty][tx] = x[(size_t)(k0 + ty) * NN + col];
    __syncthreads();
#pragma unroll
    for (int kk = 0; kk < 16; kk++) acc += sA[ty][kk] * sB[kk][tx];
    __syncthreads();
  }
  c[(size_t)row * NN + col] = acc;
}

// ---------- launcher ----------

extern "C" void kernel_launch(void* const* d_in, const int* in_sizes, int n_in,
                              void* d_out, int out_size, void* d_ws, size_t ws_size,
                              hipStream_t stream) {
  const float* x = (const float*)d_in[0];
  const float* w = (const float*)d_in[1];
  float* out = (float*)d_out;

  const size_t need = (size_t)MM * KK * 2 + (size_t)NN * KK * 2;
  if (ws_size < need) {
    dim3 blk(16, 16);
    dim3 grd(NN / 16, MM / 16);
    kfallback<<<grd, blk, 0, stream>>>(x, w, out);
    return;
  }

  unsigned short* wh = (unsigned short*)d_ws;
  unsigned short* xt = wh + (size_t)MM * KK;

  kquant<<<(MM * (size_t)KK / 8) / 256, 256, 0, stream>>>(w, wh);
  ktranspose<<<dim3(NN / 64, KK / 64), 256, 0, stream>>>(x, xt);
  kgemm<<<dim3(NN / BN, MM / BM), 512, 0, stream>>>(wh, xt, out);
}

// Round 3
// 137.050 us; speedup vs baseline: 1.6008x; 1.1398x over previous
//
#include <hip/hip_runtime.h>

#define MM 4096
#define NN 4096
#define KK 4096
#define BM 256
#define BN 256
#define BK 64
#define NT (KK / BK)

typedef short          s16x8 __attribute__((ext_vector_type(8)));
typedef float          f32x4 __attribute__((ext_vector_type(4)));
typedef unsigned short us4   __attribute__((ext_vector_type(4)));
typedef unsigned short us8   __attribute__((ext_vector_type(8)));

#define MFMA16(a, b, c) __builtin_amdgcn_mfma_f32_16x16x32_bf16((a), (b), (c), 0, 0, 0)

// ---------- helpers ----------

__device__ __forceinline__ unsigned short f2bf(float f) {
  unsigned int u = __float_as_uint(f);
  u += 0x7fffu + ((u >> 16) & 1u);
  return (unsigned short)(u >> 16);
}

__device__ __forceinline__ void gload16(const void* g, void* l) {
  __builtin_amdgcn_global_load_lds(
      (const __attribute__((address_space(1))) void*)g,
      (__attribute__((address_space(3))) void*)l, 16, 0, 0);
}

// ---------- kernel 1: 2:4 mask + binarize + cvt -> bf16 W_h (M x K) ----------

__global__ __launch_bounds__(256) void kquant(const float* __restrict__ w,
                                              unsigned short* __restrict__ wh) {
  int idx = blockIdx.x * 256 + threadIdx.x;
  const float4* p = (const float4*)w;
  float4 g0 = p[(size_t)idx * 2];
  float4 g1 = p[(size_t)idx * 2 + 1];
  float v[8] = {g0.x, g0.y, g0.z, g0.w, g1.x, g1.y, g1.z, g1.w};
  us8 o;
#pragma unroll
  for (int g = 0; g < 2; g++) {
    float av[4];
#pragma unroll
    for (int j = 0; j < 4; j++) av[j] = fabsf(v[g * 4 + j]);
#pragma unroll
    for (int j = 0; j < 4; j++) {
      int rank = 0;
#pragma unroll
      for (int k = 0; k < 4; k++) {
        if (k == j) continue;
        rank += (av[k] > av[j] || (av[k] == av[j] && k < j)) ? 1 : 0;
      }
      o[g * 4 + j] = (rank < 2 && v[g * 4 + j] > 0.0f) ? (unsigned short)0x3F80
                                                       : (unsigned short)0;
    }
  }
  *(us8*)(wh + (size_t)idx * 8) = o;
}

// ---------- kernel 2: x (K x N f32) -> xT (N x K bf16) ----------

__global__ __launch_bounds__(256) void ktranspose(const float* __restrict__ x,
                                                  unsigned short* __restrict__ xt) {
  __shared__ float tile[64][65];
  int bn = blockIdx.x;
  int bk = blockIdx.y;
  int t = threadIdx.x;
  int tc = (t & 15) << 2;
  int tr = t >> 4;
  const float* src = x + (size_t)(bk * 64 + tr) * NN + bn * 64 + tc;
#pragma unroll
  for (int i = 0; i < 4; i++) {
    float4 v = *(const float4*)(src + (size_t)i * 16 * NN);
    int r = tr + i * 16;
    tile[r][tc + 0] = v.x; tile[r][tc + 1] = v.y;
    tile[r][tc + 2] = v.z; tile[r][tc + 3] = v.w;
  }
  __syncthreads();
  unsigned short* dst = xt + (size_t)(bn * 64 + tr) * KK + bk * 64 + tc;
#pragma unroll
  for (int i = 0; i < 4; i++) {
    int n = tr + i * 16;
    us4 o;
    o.x = f2bf(tile[tc + 0][n]);
    o.y = f2bf(tile[tc + 1][n]);
    o.z = f2bf(tile[tc + 2][n]);
    o.w = f2bf(tile[tc + 3][n]);
    *(us4*)(dst + (size_t)i * 16 * KK) = o;
  }
}

// ---------- kernel 3: 256x256 true 8-phase GEMM (2 K-tiles / iter) ----------
// 8 waves (2M x 4N), BK=64, dbuf LDS (128 KiB). Staging spread 1 half-tile
// (2 gloads/thread) per phase; counted vmcnt(4) only at the 2 K-tile
// boundaries (ph4/ph8); T2 XOR swizzle; T5 setprio per MFMA cluster.

__global__ __launch_bounds__(512, 2) void kgemm(const unsigned short* __restrict__ A,
                                                const unsigned short* __restrict__ B,
                                                float* __restrict__ C) {
  __shared__ __align__(16) unsigned short lds[4 * BM * BK];  // A0|A1|B0|B1, 128 KiB

  const int tid  = threadIdx.x;
  const int bmi  = blockIdx.y;
  const int bni  = blockIdx.x;
  const int lane = tid & 63;
  const int wave = tid >> 6;
  const int wm   = wave >> 2;      // 0..1
  const int wn   = wave & 3;       // 0..3
  const int llo  = lane & 15;
  const int lhi  = lane >> 4;

  // staging addresses (linear LDS dest; inverse-swizzled global source)
  const int srow  = tid >> 3;                     // 0..63 per 64-row chunk
  const int scol  = (tid & 7) << 3;
  const int scolz = scol ^ ((srow & 7) << 3);
  const unsigned short* ga = A + (size_t)(bmi * BM + srow) * KK + scolz;
  const unsigned short* gb = B + (size_t)(bni * BN + srow) * KK + scolz;

  // fragment read offsets (swizzled)
  const int swz  = (llo & 7) << 3;
  const int ok0  = (lhi * 8) ^ swz;
  const int ok1  = (32 + lhi * 8) ^ swz;
  const int arow = (wm * 128 + llo) * BK;
  const int brow = (wn * 64 + llo) * BK;

  f32x4 acc[8][4] = {};

  auto stageA = [&](int buf, int t, int h) {   // half-tile: rows h*128..h*128+127
    const unsigned short* p = ga + (size_t)t * BK;
    unsigned short* l = &lds[buf * 16384 + tid * 8];
#pragma unroll
    for (int j = 0; j < 2; j++)
      gload16(p + (size_t)(2 * h + j) * 64 * KK, l + (2 * h + j) * 4096);
  };
  auto stageB = [&](int buf, int t, int h) {
    const unsigned short* p = gb + (size_t)t * BK;
    unsigned short* l = &lds[32768 + buf * 16384 + tid * 8];
#pragma unroll
    for (int j = 0; j < 2; j++)
      gload16(p + (size_t)(2 * h + j) * 64 * KK, l + (2 * h + j) * 4096);
  };

  // prologue: tile 0 complete -> buf0 (8 loads), A(tile 1) -> buf1 (4 loads)
  stageB(0, 0, 0); stageB(0, 0, 1);
  stageA(0, 0, 0); stageA(0, 0, 1);
  stageA(1, 1, 0); stageA(1, 1, 1);
  asm volatile("s_waitcnt vmcnt(4)" ::: "memory");   // tile 0 landed; A(1) in flight
  __builtin_amdgcn_s_barrier();

  s16x8 af[4][2], b0[2][2], b1[2][2];
  const unsigned short* sa0 = &lds[0];
  const unsigned short* sa1 = &lds[16384];
  const unsigned short* sb0 = &lds[32768];
  const unsigned short* sb1 = &lds[32768 + 16384];

  for (int it = 0; it < NT / 2; ++it) {
    const int t1 = 2 * it + 1;
    const int t2 = (2 * it + 2) & (NT - 1);   // wraps on last iter into dead regions
    const int t3 = (2 * it + 3) & (NT - 1);

    // ================= K-tile 2*it from buf0 =================
    // ---- ph1: reads af-lo + b0; stage B-h0(t1)->buf1 ----
#pragma unroll
    for (int m = 0; m < 4; m++) {
      af[m][0] = *(const s16x8*)(sa0 + arow + m * 16 * BK + ok0);
      af[m][1] = *(const s16x8*)(sa0 + arow + m * 16 * BK + ok1);
    }
#pragma unroll
    for (int n = 0; n < 2; n++) {
      b0[n][0] = *(const s16x8*)(sb0 + brow + n * 16 * BK + ok0);
      b0[n][1] = *(const s16x8*)(sb0 + brow + n * 16 * BK + ok1);
    }
    stageB(1, t1, 0);
    __builtin_amdgcn_s_barrier();
    asm volatile("s_waitcnt lgkmcnt(0)" ::: "memory");
    __builtin_amdgcn_sched_barrier(0);
    __builtin_amdgcn_s_setprio(1);
#pragma unroll
    for (int m = 0; m < 4; m++)
#pragma unroll
      for (int n = 0; n < 2; n++) {
        acc[m][n] = MFMA16(af[m][0], b0[n][0], acc[m][n]);
        acc[m][n] = MFMA16(af[m][1], b0[n][1], acc[m][n]);
      }
    __builtin_amdgcn_s_setprio(0);
    __builtin_amdgcn_s_barrier();

    // ---- ph2: reads b1; stage B-h1(t1)->buf1 ----
#pragma unroll
    for (int n = 0; n < 2; n++) {
      b1[n][0] = *(const s16x8*)(sb0 + brow + (32 + n * 16) * BK + ok0);
      b1[n][1] = *(const s16x8*)(sb0 + brow + (32 + n * 16) * BK + ok1);
    }
    stageB(1, t1, 1);
    __builtin_amdgcn_s_barrier();
    asm volatile("s_waitcnt lgkmcnt(0)" ::: "memory");
    __builtin_amdgcn_sched_barrier(0);
    __builtin_amdgcn_s_setprio(1);
#pragma unroll
    for (int m = 0; m < 4; m++)
#pragma unroll
      for (int n = 0; n < 2; n++) {
        acc[m][2 + n] = MFMA16(af[m][0], b1[n][0], acc[m][2 + n]);
        acc[m][2 + n] = MFMA16(af[m][1], b1[n][1], acc[m][2 + n]);
      }
    __builtin_amdgcn_s_setprio(0);
    __builtin_amdgcn_s_barrier();

    // ---- ph3: reads af-hi (reuse regs); stage B-h0(t2)->buf0 (B dead @ph2-end) ----
#pragma unroll
    for (int m = 0; m < 4; m++) {
      af[m][0] = *(const s16x8*)(sa0 + arow + (64 + m * 16) * BK + ok0);
      af[m][1] = *(const s16x8*)(sa0 + arow + (64 + m * 16) * BK + ok1);
    }
    stageB(0, t2, 0);
    __builtin_amdgcn_s_barrier();
    asm volatile("s_waitcnt lgkmcnt(0)" ::: "memory");
    __builtin_amdgcn_sched_barrier(0);
    __builtin_amdgcn_s_setprio(1);
#pragma unroll
    for (int m = 0; m < 4; m++)
#pragma unroll
      for (int n = 0; n < 2; n++) {
        acc[4 + m][n] = MFMA16(af[m][0], b0[n][0], acc[4 + m][n]);
        acc[4 + m][n] = MFMA16(af[m][1], b0[n][1], acc[4 + m][n]);
      }
    __builtin_amdgcn_s_setprio(0);
    __builtin_amdgcn_s_barrier();

    // ---- ph4: stage B-h1(t2)->buf0; MFMA Q11; vmcnt(4) boundary ----
    stageB(0, t2, 1);
    __builtin_amdgcn_s_setprio(1);
#pragma unroll
    for (int m = 0; m < 4; m++)
#pragma unroll
      for (int n = 0; n < 2; n++) {
        acc[4 + m][2 + n] = MFMA16(af[m][0], b1[n][0], acc[4 + m][2 + n]);
        acc[4 + m][2 + n] = MFMA16(af[m][1], b1[n][1], acc[4 + m][2 + n]);
      }
    __builtin_amdgcn_s_setprio(0);
    // newest 4 gloads = B(t2); everything older (A(t1), B(t1)) landed
    asm volatile("s_waitcnt vmcnt(4)" ::: "memory");
    __builtin_amdgcn_s_barrier();

    // ================= K-tile 2*it+1 from buf1 =================
    // ---- ph5: reads af-lo + b0; stage A-h0(t2)->buf0 (A dead @ph3-end) ----
#pragma unroll
    for (int m = 0; m < 4; m++) {
      af[m][0] = *(const s16x8*)(sa1 + arow + m * 16 * BK + ok0);
      af[m][1] = *(const s16x8*)(sa1 + arow + m * 16 * BK + ok1);
    }
#pragma unroll
    for (int n = 0; n < 2; n++) {
      b0[n][0] = *(const s16x8*)(sb1 + brow + n * 16 * BK + ok0);
      b0[n][1] = *(const s16x8*)(sb1 + brow + n * 16 * BK + ok1);
    }
    stageA(0, t2, 0);
    __builtin_amdgcn_s_barrier();
    asm volatile("s_waitcnt lgkmcnt(0)" ::: "memory");
    __builtin_amdgcn_sched_barrier(0);
    __builtin_amdgcn_s_setprio(1);
#pragma unroll
    for (int m = 0; m < 4; m++)
#pragma unroll
      for (int n = 0; n < 2; n++) {
        acc[m][n] = MFMA16(af[m][0], b0[n][0], acc[m][n]);
        acc[m][n] = MFMA16(af[m][1], b0[n][1], acc[m][n]);
      }
    __builtin_amdgcn_s_setprio(0);
    __builtin_amdgcn_s_barrier();

    // ---- ph6: reads b1; stage A-h1(t2)->buf0 ----
#pragma unroll
    for (int n = 0; n < 2; n++) {
      b1[n][0] = *(const s16x8*)(sb1 + brow + (32 + n * 16) * BK + ok0);
      b1[n][1] = *(const s16x8*)(sb1 + brow + (32 + n * 16) * BK + ok1);
    }
    stageA(0, t2, 1);
    __builtin_amdgcn_s_barrier();
    asm volatile("s_waitcnt lgkmcnt(0)" ::: "memory");
    __builtin_amdgcn_sched_barrier(0);
    __builtin_amdgcn_s_setprio(1);
#pragma unroll
    for (int m = 0; m < 4; m++)
#pragma unroll
      for (int n = 0; n < 2; n++) {
        acc[m][2 + n] = MFMA16(af[m][0], b1[n][0], acc[m][2 + n]);
        acc[m][2 + n] = MFMA16(af[m][1], b1[n][1], acc[m][2 + n]);
      }
    __builtin_amdgcn_s_setprio(0);
    __builtin_amdgcn_s_barrier();

    // ---- ph7: reads af-hi; no stage ----
#pragma unroll
    for (int m = 0; m < 4; m++) {
      af[m][0] = *(const s16x8*)(sa1 + arow + (64 + m * 16) * BK + ok0);
      af[m][1] = *(const s16x8*)(sa1 + arow + (64 + m * 16) * BK + ok1);
    }
    __builtin_amdgcn_s_barrier();
    asm volatile("s_waitcnt lgkmcnt(0)" ::: "memory");
    __builtin_amdgcn_sched_barrier(0);
    __builtin_amdgcn_s_setprio(1);
#pragma unroll
    for (int m = 0; m < 4; m++)
#pragma unroll
      for (int n = 0; n < 2; n++) {
        acc[4 + m][n] = MFMA16(af[m][0], b0[n][0], acc[4 + m][n]);
        acc[4 + m][n] = MFMA16(af[m][1], b0[n][1], acc[4 + m][n]);
      }
    __builtin_amdgcn_s_setprio(0);
    __builtin_amdgcn_s_barrier();

    // ---- ph8: stage A-h0+h1(t3)->buf1 (A dead @ph7-end); MFMA Q11; vmcnt(4) ----
    stageA(1, t3, 0);
    stageA(1, t3, 1);
    __builtin_amdgcn_s_setprio(1);
#pragma unroll
    for (int m = 0; m < 4; m++)
#pragma unroll
      for (int n = 0; n < 2; n++) {
        acc[4 + m][2 + n] = MFMA16(af[m][0], b1[n][0], acc[4 + m][2 + n]);
        acc[4 + m][2 + n] = MFMA16(af[m][1], b1[n][1], acc[4 + m][2 + n]);
      }
    __builtin_amdgcn_s_setprio(0);
    // newest 4 gloads = A(t3); B(t2) [ph3,4] and A(t2) [ph5,6] landed
    asm volatile("s_waitcnt vmcnt(4)" ::: "memory");
    __builtin_amdgcn_s_barrier();
  }

  // ---- epilogue: D layout col = lane&15, row = (lane>>4)*4 + reg ----
  const int crow0 = bmi * BM + wm * 128 + lhi * 4;
  const int ccol0 = bni * BN + wn * 64 + llo;
#pragma unroll
  for (int m = 0; m < 8; m++)
#pragma unroll
    for (int n = 0; n < 4; n++) {
      float* cp = C + (size_t)(crow0 + m * 16) * NN + ccol0 + n * 16;
#pragma unroll
      for (int v = 0; v < 4; v++) cp[(size_t)v * NN] = acc[m][n][v];
    }
}

// ---------- fallback: fused fp32 tiled GEMM (workspace too small) ----------

__device__ __forceinline__ float binq_elem(const float g[4], int j) {
  float aj = fabsf(g[j]);
  int rank = 0;
#pragma unroll
  for (int k = 0; k < 4; k++) {
    if (k == j) continue;
    float ak = fabsf(g[k]);
    rank += (ak > aj || (ak == aj && k < j)) ? 1 : 0;
  }
  return (rank < 2 && g[j] > 0.0f) ? 1.0f : 0.0f;
}

__global__ __launch_bounds__(256) void kfallback(const float* __restrict__ x,
                                                 const float* __restrict__ w,
                                                 float* __restrict__ c) {
  __shared__ float sA[16][17];
  __shared__ float sB[16][17];
  int tx = threadIdx.x, ty = threadIdx.y;
  int row = blockIdx.y * 16 + ty;
  int col = blockIdx.x * 16 + tx;
  float acc = 0.0f;
  for (int k0 = 0; k0 < KK; k0 += 16) {
    int k = k0 + tx;
    const float* g = &w[(size_t)row * KK + (k & ~3)];
    float gv[4] = {g[0], g[1], g[2], g[3]};
    sA[ty][tx] = binq_elem(gv, k & 3);
    sB[ty][tx] = x[(size_t)(k0 + ty) * NN + col];
    __syncthreads();
#pragma unroll
    for (int kk = 0; kk < 16; kk++) acc += sA[ty][kk] * sB[kk][tx];
    __syncthreads();
  }
  c[(size_t)row * NN + col] = acc;
}

// ---------- launcher ----------

extern "C" void kernel_launch(void* const* d_in, const int* in_sizes, int n_in,
                              void* d_out, int out_size, void* d_ws, size_t ws_size,
                              hipStream_t stream) {
  const float* x = (const float*)d_in[0];
  const float* w = (const float*)d_in[1];
  float* out = (float*)d_out;

  const size_t need = (size_t)MM * KK * 2 + (size_t)NN * KK * 2;
  if (ws_size < need) {
    dim3 blk(16, 16);
    dim3 grd(NN / 16, MM / 16);
    kfallback<<<grd, blk, 0, stream>>>(x, w, out);
    return;
  }

  unsigned short* wh = (unsigned short*)d_ws;
  unsigned short* xt = wh + (size_t)MM * KK;

  kquant<<<(MM * (size_t)KK / 8) / 256, 256, 0, stream>>>(w, wh);
  ktranspose<<<dim3(NN / 64, KK / 64), 256, 0, stream>>>(x, xt);
  kgemm<<<dim3(NN / BN, MM / BM), 512, 0, stream>>>(wh, xt, out);
}

// Round 4
// 135.196 us; speedup vs baseline: 1.6227x; 1.0137x over previous
//
#include <hip/hip_runtime.h>

#define MM 4096
#define NN 4096
#define KK 4096
#define BM 256
#define BN 256
#define BK 64
#define NT (KK / BK)

typedef short          s16x8 __attribute__((ext_vector_type(8)));
typedef float          f32x4 __attribute__((ext_vector_type(4)));
typedef unsigned short us4   __attribute__((ext_vector_type(4)));
typedef unsigned short us8   __attribute__((ext_vector_type(8)));

#define MFMA16(a, b, c) __builtin_amdgcn_mfma_f32_16x16x32_bf16((a), (b), (c), 0, 0, 0)
#define SB0() __builtin_amdgcn_sched_barrier(0)
#define LGKM(n) asm volatile("s_waitcnt lgkmcnt(" #n ")" ::: "memory")
#define VMC(n)  asm volatile("s_waitcnt vmcnt(" #n ")" ::: "memory")

// ---------- helpers ----------

__device__ __forceinline__ unsigned short f2bf(float f) {
  unsigned int u = __float_as_uint(f);
  u += 0x7fffu + ((u >> 16) & 1u);
  return (unsigned short)(u >> 16);
}

__device__ __forceinline__ void gload16(const void* g, void* l) {
  __builtin_amdgcn_global_load_lds(
      (const __attribute__((address_space(1))) void*)g,
      (__attribute__((address_space(3))) void*)l, 16, 0, 0);
}

// ---------- kernel 1: 2:4 mask + binarize + cvt -> bf16 W_h (M x K) ----------

__global__ __launch_bounds__(256) void kquant(const float* __restrict__ w,
                                              unsigned short* __restrict__ wh) {
  int idx = blockIdx.x * 256 + threadIdx.x;
  const float4* p = (const float4*)w;
  float4 g0 = p[(size_t)idx * 2];
  float4 g1 = p[(size_t)idx * 2 + 1];
  float v[8] = {g0.x, g0.y, g0.z, g0.w, g1.x, g1.y, g1.z, g1.w};
  us8 o;
#pragma unroll
  for (int g = 0; g < 2; g++) {
    float av[4];
#pragma unroll
    for (int j = 0; j < 4; j++) av[j] = fabsf(v[g * 4 + j]);
#pragma unroll
    for (int j = 0; j < 4; j++) {
      int rank = 0;
#pragma unroll
      for (int k = 0; k < 4; k++) {
        if (k == j) continue;
        rank += (av[k] > av[j] || (av[k] == av[j] && k < j)) ? 1 : 0;
      }
      o[g * 4 + j] = (rank < 2 && v[g * 4 + j] > 0.0f) ? (unsigned short)0x3F80
                                                       : (unsigned short)0;
    }
  }
  *(us8*)(wh + (size_t)idx * 8) = o;
}

// ---------- kernel 2: x (K x N f32) -> xT (N x K bf16) ----------

__global__ __launch_bounds__(256) void ktranspose(const float* __restrict__ x,
                                                  unsigned short* __restrict__ xt) {
  __shared__ float tile[64][65];
  int bn = blockIdx.x;
  int bk = blockIdx.y;
  int t = threadIdx.x;
  int tc = (t & 15) << 2;
  int tr = t >> 4;
  const float* src = x + (size_t)(bk * 64 + tr) * NN + bn * 64 + tc;
#pragma unroll
  for (int i = 0; i < 4; i++) {
    float4 v = *(const float4*)(src + (size_t)i * 16 * NN);
    int r = tr + i * 16;
    tile[r][tc + 0] = v.x; tile[r][tc + 1] = v.y;
    tile[r][tc + 2] = v.z; tile[r][tc + 3] = v.w;
  }
  __syncthreads();
  unsigned short* dst = xt + (size_t)(bn * 64 + tr) * KK + bk * 64 + tc;
#pragma unroll
  for (int i = 0; i < 4; i++) {
    int n = tr + i * 16;
    us4 o;
    o.x = f2bf(tile[tc + 0][n]);
    o.y = f2bf(tile[tc + 1][n]);
    o.z = f2bf(tile[tc + 2][n]);
    o.w = f2bf(tile[tc + 3][n]);
    *(us4*)(dst + (size_t)i * 16 * KK) = o;
  }
}

// ---------- kernel 3: 256x256 8-phase GEMM, one-phase-ahead ds_read pipeline --
// 8 waves (2M x 4N), BK=64, dbuf LDS. Reads for phase p+1 issued before phase
// p's MFMA cluster with counted lgkmcnt (0/8/0) so the LDS pipe drains UNDER
// the MFMA pipe instead of serializing. Staging calendar + vmcnt(4) boundaries
// identical to the verified round-3 schedule.

__global__ __launch_bounds__(512, 2) void kgemm(const unsigned short* __restrict__ A,
                                                const unsigned short* __restrict__ B,
                                                float* __restrict__ C) {
  __shared__ __align__(16) unsigned short lds[4 * BM * BK];  // A0|A1|B0|B1, 128 KiB

  const int tid  = threadIdx.x;
  const int bmi  = blockIdx.y;
  const int bni  = blockIdx.x;
  const int lane = tid & 63;
  const int wave = tid >> 6;
  const int wm   = wave >> 2;
  const int wn   = wave & 3;
  const int llo  = lane & 15;
  const int lhi  = lane >> 4;

  // staging addresses (linear LDS dest; inverse-swizzled global source)
  const int srow  = tid >> 3;
  const int scol  = (tid & 7) << 3;
  const int scolz = scol ^ ((srow & 7) << 3);
  const unsigned short* ga = A + (size_t)(bmi * BM + srow) * KK + scolz;
  const unsigned short* gb = B + (size_t)(bni * BN + srow) * KK + scolz;

  // fragment read offsets (swizzled)
  const int swz  = (llo & 7) << 3;
  const int ok0  = (lhi * 8) ^ swz;
  const int ok1  = (32 + lhi * 8) ^ swz;
  const int arow = (wm * 128 + llo) * BK;
  const int brow = (wn * 64 + llo) * BK;

  f32x4 acc[8][4] = {};

  auto stageA = [&](int buf, int t, int h) {
    const unsigned short* p = ga + (size_t)t * BK;
    unsigned short* l = &lds[buf * 16384 + tid * 8];
#pragma unroll
    for (int j = 0; j < 2; j++)
      gload16(p + (size_t)(2 * h + j) * 64 * KK, l + (2 * h + j) * 4096);
  };
  auto stageB = [&](int buf, int t, int h) {
    const unsigned short* p = gb + (size_t)t * BK;
    unsigned short* l = &lds[32768 + buf * 16384 + tid * 8];
#pragma unroll
    for (int j = 0; j < 2; j++)
      gload16(p + (size_t)(2 * h + j) * 64 * KK, l + (2 * h + j) * 4096);
  };

  // prologue: tile 0 -> buf0 (8 loads), A(tile 1) -> buf1 (4 loads)
  stageB(0, 0, 0); stageB(0, 0, 1);
  stageA(0, 0, 0); stageA(0, 0, 1);
  stageA(1, 1, 0); stageA(1, 1, 1);
  VMC(4);                      // tile 0 landed; A(1) in flight
  __builtin_amdgcn_s_barrier();

  s16x8 af[4][2], af2[4][2], b0[2][2], b1[2][2];
  const unsigned short* sa0 = &lds[0];
  const unsigned short* sa1 = &lds[16384];
  const unsigned short* sb0 = &lds[32768];
  const unsigned short* sb1 = &lds[32768 + 16384];

  for (int it = 0; it < NT / 2; ++it) {
    const int t1 = 2 * it + 1;
    const int t2 = (2 * it + 2) & (NT - 1);   // wraps on last iter (dead regions)
    const int t3 = (2 * it + 3) & (NT - 1);

    // ================= K-tile 2*it from buf0 =================
    // P1: wait entry reads; issue b1+af2 (drain under Q00/Q01); stage; Q00
#pragma unroll
    for (int m = 0; m < 4; m++) {
      af[m][0] = *(const s16x8*)(sa0 + arow + m * 16 * BK + ok0);
      af[m][1] = *(const s16x8*)(sa0 + arow + m * 16 * BK + ok1);
    }
#pragma unroll
    for (int n = 0; n < 2; n++) {
      b0[n][0] = *(const s16x8*)(sb0 + brow + n * 16 * BK + ok0);
      b0[n][1] = *(const s16x8*)(sb0 + brow + n * 16 * BK + ok1);
    }
    LGKM(0); SB0();
#pragma unroll
    for (int n = 0; n < 2; n++) {
      b1[n][0] = *(const s16x8*)(sb0 + brow + (32 + n * 16) * BK + ok0);
      b1[n][1] = *(const s16x8*)(sb0 + brow + (32 + n * 16) * BK + ok1);
    }
#pragma unroll
    for (int m = 0; m < 4; m++) {
      af2[m][0] = *(const s16x8*)(sa0 + arow + (64 + m * 16) * BK + ok0);
      af2[m][1] = *(const s16x8*)(sa0 + arow + (64 + m * 16) * BK + ok1);
    }
    stageB(1, t1, 0);
    __builtin_amdgcn_s_setprio(1);
#pragma unroll
    for (int m = 0; m < 4; m++)
#pragma unroll
      for (int n = 0; n < 2; n++) {
        acc[m][n] = MFMA16(af[m][0], b0[n][0], acc[m][n]);
        acc[m][n] = MFMA16(af[m][1], b0[n][1], acc[m][n]);
      }
    __builtin_amdgcn_s_setprio(0);
    SB0(); __builtin_amdgcn_s_barrier();

    // P2: b1 ready (af2 may linger); stage; Q01
    LGKM(8); SB0();
    stageB(1, t1, 1);
    __builtin_amdgcn_s_setprio(1);
#pragma unroll
    for (int m = 0; m < 4; m++)
#pragma unroll
      for (int n = 0; n < 2; n++) {
        acc[m][2 + n] = MFMA16(af[m][0], b1[n][0], acc[m][2 + n]);
        acc[m][2 + n] = MFMA16(af[m][1], b1[n][1], acc[m][2 + n]);
      }
    __builtin_amdgcn_s_setprio(0);
    SB0(); __builtin_amdgcn_s_barrier();

    // P3: af2 ready; stage B(t2)->buf0 (B region dead since P2 barrier); Q10
    LGKM(0); SB0();
    stageB(0, t2, 0);
    __builtin_amdgcn_s_setprio(1);
#pragma unroll
    for (int m = 0; m < 4; m++)
#pragma unroll
      for (int n = 0; n < 2; n++) {
        acc[4 + m][n] = MFMA16(af2[m][0], b0[n][0], acc[4 + m][n]);
        acc[4 + m][n] = MFMA16(af2[m][1], b0[n][1], acc[4 + m][n]);
      }
    __builtin_amdgcn_s_setprio(0);
    SB0(); __builtin_amdgcn_s_barrier();

    // P4: stage; Q11; boundary vmcnt(4) -> A(t1),B(t1) landed; B(t2) flying
    stageB(0, t2, 1);
    __builtin_amdgcn_s_setprio(1);
#pragma unroll
    for (int m = 0; m < 4; m++)
#pragma unroll
      for (int n = 0; n < 2; n++) {
        acc[4 + m][2 + n] = MFMA16(af2[m][0], b1[n][0], acc[4 + m][2 + n]);
        acc[4 + m][2 + n] = MFMA16(af2[m][1], b1[n][1], acc[4 + m][2 + n]);
      }
    __builtin_amdgcn_s_setprio(0);
    VMC(4);
    SB0(); __builtin_amdgcn_s_barrier();

    // ================= K-tile 2*it+1 from buf1 =================
    // P5
#pragma unroll
    for (int m = 0; m < 4; m++) {
      af[m][0] = *(const s16x8*)(sa1 + arow + m * 16 * BK + ok0);
      af[m][1] = *(const s16x8*)(sa1 + arow + m * 16 * BK + ok1);
    }
#pragma unroll
    for (int n = 0; n < 2; n++) {
      b0[n][0] = *(const s16x8*)(sb1 + brow + n * 16 * BK + ok0);
      b0[n][1] = *(const s16x8*)(sb1 + brow + n * 16 * BK + ok1);
    }
    LGKM(0); SB0();
#pragma unroll
    for (int n = 0; n < 2; n++) {
      b1[n][0] = *(const s16x8*)(sb1 + brow + (32 + n * 16) * BK + ok0);
      b1[n][1] = *(const s16x8*)(sb1 + brow + (32 + n * 16) * BK + ok1);
    }
#pragma unroll
    for (int m = 0; m < 4; m++) {
      af2[m][0] = *(const s16x8*)(sa1 + arow + (64 + m * 16) * BK + ok0);
      af2[m][1] = *(const s16x8*)(sa1 + arow + (64 + m * 16) * BK + ok1);
    }
    stageA(0, t2, 0);          // buf0 A region dead since P3 barrier of prev... (P3 of this iter reads af2 from sa0 — completed by P3 barrier)
    __builtin_amdgcn_s_setprio(1);
#pragma unroll
    for (int m = 0; m < 4; m++)
#pragma unroll
      for (int n = 0; n < 2; n++) {
        acc[m][n] = MFMA16(af[m][0], b0[n][0], acc[m][n]);
        acc[m][n] = MFMA16(af[m][1], b0[n][1], acc[m][n]);
      }
    __builtin_amdgcn_s_setprio(0);
    SB0(); __builtin_amdgcn_s_barrier();

    // P6
    LGKM(8); SB0();
    stageA(0, t2, 1);
    __builtin_amdgcn_s_setprio(1);
#pragma unroll
    for (int m = 0; m < 4; m++)
#pragma unroll
      for (int n = 0; n < 2; n++) {
        acc[m][2 + n] = MFMA16(af[m][0], b1[n][0], acc[m][2 + n]);
        acc[m][2 + n] = MFMA16(af[m][1], b1[n][1], acc[m][2 + n]);
      }
    __builtin_amdgcn_s_setprio(0);
    SB0(); __builtin_amdgcn_s_barrier();

    // P7: no stage
    LGKM(0); SB0();
    __builtin_amdgcn_s_setprio(1);
#pragma unroll
    for (int m = 0; m < 4; m++)
#pragma unroll
      for (int n = 0; n < 2; n++) {
        acc[4 + m][n] = MFMA16(af2[m][0], b0[n][0], acc[4 + m][n]);
        acc[4 + m][n] = MFMA16(af2[m][1], b0[n][1], acc[4 + m][n]);
      }
    __builtin_amdgcn_s_setprio(0);
    SB0(); __builtin_amdgcn_s_barrier();

    // P8: stage A(t3)->buf1 (A region read-complete by P7 barrier); Q11; vmcnt(4)
    stageA(1, t3, 0);
    stageA(1, t3, 1);
    __builtin_amdgcn_s_setprio(1);
#pragma unroll
    for (int m = 0; m < 4; m++)
#pragma unroll
      for (int n = 0; n < 2; n++) {
        acc[4 + m][2 + n] = MFMA16(af2[m][0], b1[n][0], acc[4 + m][2 + n]);
        acc[4 + m][2 + n] = MFMA16(af2[m][1], b1[n][1], acc[4 + m][2 + n]);
      }
    __builtin_amdgcn_s_setprio(0);
    VMC(4);                    // B(t2),A(t2) landed; A(t3) flying
    SB0(); __builtin_amdgcn_s_barrier();
  }

  // ---- epilogue: D layout col = lane&15, row = (lane>>4)*4 + reg ----
  const int crow0 = bmi * BM + wm * 128 + lhi * 4;
  const int ccol0 = bni * BN + wn * 64 + llo;
#pragma unroll
  for (int m = 0; m < 8; m++)
#pragma unroll
    for (int n = 0; n < 4; n++) {
      float* cp = C + (size_t)(crow0 + m * 16) * NN + ccol0 + n * 16;
#pragma unroll
      for (int v = 0; v < 4; v++) cp[(size_t)v * NN] = acc[m][n][v];
    }
}

// ---------- fallback: fused fp32 tiled GEMM (workspace too small) ----------

__device__ __forceinline__ float binq_elem(const float g[4], int j) {
  float aj = fabsf(g[j]);
  int rank = 0;
#pragma unroll
  for (int k = 0; k < 4; k++) {
    if (k == j) continue;
    float ak = fabsf(g[k]);
    rank += (ak > aj || (ak == aj && k < j)) ? 1 : 0;
  }
  return (rank < 2 && g[j] > 0.0f) ? 1.0f : 0.0f;
}

__global__ __launch_bounds__(256) void kfallback(const float* __restrict__ x,
                                                 const float* __restrict__ w,
                                                 float* __restrict__ c) {
  __shared__ float sA[16][17];
  __shared__ float sB[16][17];
  int tx = threadIdx.x, ty = threadIdx.y;
  int row = blockIdx.y * 16 + ty;
  int col = blockIdx.x * 16 + tx;
  float acc = 0.0f;
  for (int k0 = 0; k0 < KK; k0 += 16) {
    int k = k0 + tx;
    const float* g = &w[(size_t)row * KK + (k & ~3)];
    float gv[4] = {g[0], g[1], g[2], g[3]};
    sA[ty][tx] = binq_elem(gv, k & 3);
    sB[ty][tx] = x[(size_t)(k0 + ty) * NN + col];
    __syncthreads();
#pragma unroll
    for (int kk = 0; kk < 16; kk++) acc += sA[ty][kk] * sB[kk][tx];
    __syncthreads();
  }
  c[(size_t)row * NN + col] = acc;
}

// ---------- launcher ----------

extern "C" void kernel_launch(void* const* d_in, const int* in_sizes, int n_in,
                              void* d_out, int out_size, void* d_ws, size_t ws_size,
                              hipStream_t stream) {
  const float* x = (const float*)d_in[0];
  const float* w = (const float*)d_in[1];
  float* out = (float*)d_out;

  const size_t need = (size_t)MM * KK * 2 + (size_t)NN * KK * 2;
  if (ws_size < need) {
    dim3 blk(16, 16);
    dim3 grd(NN / 16, MM / 16);
    kfallback<<<grd, blk, 0, stream>>>(x, w, out);
    return;
  }

  unsigned short* wh = (unsigned short*)d_ws;
  unsigned short* xt = wh + (size_t)MM * KK;

  kquant<<<(MM * (size_t)KK / 8) / 256, 256, 0, stream>>>(w, wh);
  ktranspose<<<dim3(NN / 64, KK / 64), 256, 0, stream>>>(x, xt);
  kgemm<<<dim3(NN / BN, MM / BM), 512, 0, stream>>>(wh, xt, out);
}